// Round 15
// baseline (11270.261 us; speedup 1.0000x reference)
//
#include <hip/hip_runtime.h>
#include <hip/hip_bf16.h>
#include <math.h>

#define E_ 7
#define B_ 50
#define T_ 100
#define D_ 128
#define A_ 32
#define L_ 256
#define H_ 1024
#define C_ 128
#define EB_ 350
#define TB_ 5000
#define SQRTH 0.31622776601683794f
#define MC 198  // encoder fold chunk rows per e (25 chunks cover 50..4999)

typedef __attribute__((ext_vector_type(8))) short s8v;
typedef __attribute__((ext_vector_type(4))) float f32x4;
typedef _Float16 f16x2 __attribute__((ext_vector_type(2)));
typedef __hip_bfloat16 bf16;

#define MFMA __builtin_amdgcn_mfma_f32_16x16x32_bf16

__device__ __forceinline__ int lswz(int row, int ck) {
  return (((ck & ~7) | ((ck ^ row) & 7)) << 3);
}

struct BG {
  const bf16* A[8];
  const bf16* W[8];
  const float* bias[8];
  float* Cf[8];
  bf16* Cb[8];
};

// ---------------- bf16 MFMA GEMM (validated round 2; only axw now) ----------------
template<int BM, int ACT, int OUT>
__global__ __launch_bounds__(256)
void bgemm(BG g, int M, int K, int lda, int ldw, int ldc) {
  __shared__ short As[BM * 64];
  __shared__ short Ws[128 * 64];
  const short* Ap = (const short*)g.A[blockIdx.z];
  const short* Wp = (const short*)g.W[blockIdx.z];
  const int bm = blockIdx.x * BM, bn = blockIdx.y * 128;
  const int tid = threadIdx.x;
  const int wv = tid >> 6, lane = tid & 63;
  const int wm0 = (wv >> 1) * (BM / 2), wn0 = (wv & 1) * 64;
  const int l15 = lane & 15, l4 = lane >> 4;
  constexpr int FM = BM / 32;
  constexpr int AI = BM / 32;
  f32x4 acc[FM][4] = {};
  for (int k0 = 0; k0 < K; k0 += 64) {
    s8v av[AI], wvv[4];
#pragma unroll
    for (int i = 0; i < AI; ++i) {
      const int c = tid + i * 256, r = c >> 3, ck = c & 7;
      s8v v = {};
      if (bm + r < M) v = *(const s8v*)(Ap + (size_t)(bm + r) * lda + k0 + ck * 8);
      av[i] = v;
    }
#pragma unroll
    for (int i = 0; i < 4; ++i) {
      const int c = tid + i * 256, r = c >> 3, ck = c & 7;
      wvv[i] = *(const s8v*)(Wp + (size_t)(bn + r) * ldw + k0 + ck * 8);
    }
    __syncthreads();
#pragma unroll
    for (int i = 0; i < AI; ++i) {
      const int c = tid + i * 256, r = c >> 3, ck = c & 7;
      *(s8v*)(As + r * 64 + ((ck ^ (r & 7)) << 3)) = av[i];
    }
#pragma unroll
    for (int i = 0; i < 4; ++i) {
      const int c = tid + i * 256, r = c >> 3, ck = c & 7;
      *(s8v*)(Ws + r * 64 + ((ck ^ (r & 7)) << 3)) = wvv[i];
    }
    __syncthreads();
#pragma unroll
    for (int ks = 0; ks < 2; ++ks) {
      s8v af[FM], bfr[4];
#pragma unroll
      for (int m = 0; m < FM; ++m) {
        const int r = wm0 + m * 16 + l15, ck = ks * 4 + l4;
        af[m] = *(const s8v*)(As + r * 64 + ((ck ^ (r & 7)) << 3));
      }
#pragma unroll
      for (int n = 0; n < 4; ++n) {
        const int r = wn0 + n * 16 + l15, ck = ks * 4 + l4;
        bfr[n] = *(const s8v*)(Ws + r * 64 + ((ck ^ (r & 7)) << 3));
      }
#pragma unroll
      for (int m = 0; m < FM; ++m)
#pragma unroll
        for (int n = 0; n < 4; ++n)
          acc[m][n] = MFMA(af[m], bfr[n], acc[m][n], 0, 0, 0);
    }
    __syncthreads();
  }
  const float* bias = g.bias[blockIdx.z];
  float* Cf = g.Cf[blockIdx.z];
  bf16* Cb = g.Cb[blockIdx.z];
#pragma unroll
  for (int n = 0; n < 4; ++n) {
    const int col = bn + wn0 + n * 16 + l15;
    const float bv = bias ? bias[col] : 0.f;
#pragma unroll
    for (int m = 0; m < FM; ++m) {
#pragma unroll
      for (int j = 0; j < 4; ++j) {
        const int row = bm + wm0 + m * 16 + l4 * 4 + j;
        if (row < M) {
          float v = acc[m][n][j] + bv;
          if (ACT == 1) v = fmaxf(v, 0.f);
          if (ACT == 2) v = tanhf(v);
          if (OUT == 0) Cf[(size_t)row * ldc + col] = v;
          if (OUT == 1) Cb[(size_t)row * ldc + col] = __float2bfloat16(v);
        }
      }
    }
  }
}

// ---------------- generic e-pure 16-row x 128-col tile GEMM (frag-major W) ----------------
__device__ void tile_gemm(short* As, const short* Arow, int nrows, int lda, int K,
                          const short* Wf, int ngBase, const float* bias,
                          float* CfRow0, bf16* CbRow0, int ldc, int act, int tid) {
  const int lane = tid & 63, wv = tid >> 6, l15 = lane & 15, l4 = lane >> 4;
  const int K8 = K >> 3;
  for (int i = tid; i < (K8 << 4); i += 256) {
    const int row = i / K8, ck = i - row * K8;
    s8v v = {};
    if (row < nrows) v = *(const s8v*)(Arow + (size_t)row * lda + ck * 8);
    *(s8v*)(As + row * K + lswz(row, ck)) = v;
  }
  __syncthreads();
  const int Kt = K >> 5;
  f32x4 acc0 = {}, acc1 = {};
  const int ng0 = ngBase + wv * 2;
  for (int kt = 0; kt < Kt; ++kt) {
    const int ck = kt * 4 + l4;
    const s8v a = *(const s8v*)(As + l15 * K + lswz(l15, ck));
    const s8v b0 = *(const s8v*)(Wf + ((size_t)(ng0 * Kt + kt)) * 512 + (size_t)lane * 8);
    const s8v b1 = *(const s8v*)(Wf + ((size_t)((ng0 + 1) * Kt + kt)) * 512 + (size_t)lane * 8);
    acc0 = MFMA(a, b0, acc0, 0, 0, 0);
    acc1 = MFMA(a, b1, acc1, 0, 0, 0);
  }
#pragma unroll
  for (int nt = 0; nt < 2; ++nt) {
    const f32x4 acc = nt ? acc1 : acc0;
    const int col = (ng0 + nt) * 16 + l15;
    const float bv = bias ? bias[col] : 0.f;
#pragma unroll
    for (int j = 0; j < 4; ++j) {
      const int r = l4 * 4 + j;
      if (r < nrows) {
        float v = acc[j] + bv;
        if (act == 1) v = fmaxf(v, 0.f);
        if (act == 2) v = tanhf(v);
        if (CbRow0) CbRow0[(size_t)r * ldc + col] = __float2bfloat16(v);
        else CfRow0[(size_t)r * ldc + col] = v;
      }
    }
  }
}

// standalone wrapper: grid (rt, ntb, e)
__global__ __launch_bounds__(256)
void sgemm_e(const bf16* Abf, long aEstride, long aBase, int lda, int nrowsPerE,
             const bf16* Wf, long wEstride, int K,
             const float* bias, int bEstride,
             float* Cf, bf16* Cb, long cEstride, long cBase, int ldc, int act) {
  __shared__ short As[16 * 1024];
  const int rt = blockIdx.x, ntb = blockIdx.y, e = blockIdx.z;
  const int r0 = rt * 16;
  int nrows = nrowsPerE - r0;
  if (nrows > 16) nrows = 16;
  const size_t co = (size_t)e * cEstride + cBase + (size_t)r0 * ldc;
  tile_gemm(As, (const short*)Abf + (size_t)e * aEstride + aBase + (size_t)r0 * lda,
            nrows, lda, K, (const short*)Wf + (size_t)e * wEstride, ntb * 8,
            bias + (size_t)e * bEstride,
            Cf ? Cf + co : nullptr, Cb ? Cb + co : nullptr, ldc, act, threadIdx.x);
}

// ---------------- conversions / packing ----------------
struct B4 { bf16 a, b, c, d; };
__global__ __launch_bounds__(256)
void cvt_kernel(const float* __restrict__ s, bf16* __restrict__ d, int n4) {
  const int i = blockIdx.x * 256 + threadIdx.x;
  if (i < n4) {
    const float4 v = ((const float4*)s)[i];
    B4 o = {__float2bfloat16(v.x), __float2bfloat16(v.y),
            __float2bfloat16(v.z), __float2bfloat16(v.w)};
    ((B4*)d)[i] = o;
  }
}

__global__ __launch_bounds__(256)
void packW(const float* __restrict__ src, bf16* __restrict__ dst, int K, int N) {
  const int idx = blockIdx.x * 256 + threadIdx.x;
  if (idx >= K * N) return;
  const int k = idx / N, n = idx - k * N;
  const size_t fo = ((size_t)(n >> 4) * (K >> 5) + (k >> 5)) * 512 +
                    (((k >> 3) & 3) << 7) + ((n & 15) << 3) + (k & 7);
  dst[fo] = __float2bfloat16(src[idx]);
}

__global__ __launch_bounds__(256)
void packWE(const float* __restrict__ src, bf16* __restrict__ dst, int K, int N,
            long sE, long dE) {
  const int e = blockIdx.z;
  const int idx = blockIdx.x * 256 + threadIdx.x;
  if (idx >= K * N) return;
  const int k = idx / N, n = idx - k * N;
  const size_t fo = ((size_t)(n >> 4) * (K >> 5) + (k >> 5)) * 512 +
                    (((k >> 3) & 3) << 7) + ((n & 15) << 3) + (k & 7);
  dst[(size_t)e * dE + fo] = __float2bfloat16(src[(size_t)e * sE + idx]);
}

__global__ __launch_bounds__(256)
void packWz(const float* __restrict__ act_w, bf16* __restrict__ hi, bf16* __restrict__ lo) {
  const int idx = blockIdx.x * 256 + threadIdx.x;
  if (idx >= E_ * 65536) return;
  const int e = idx >> 16, rem = idx & 65535, k = rem >> 8, n = rem & 255;
  const float w = act_w[(size_t)e * 416 * 256 + (size_t)k * 256 + n];
  const bf16 h = __float2bfloat16(w);
  const size_t fo = (size_t)e * 65536 + ((size_t)(n >> 4) * 8 + (k >> 5)) * 512 +
                    (((k >> 3) & 3) << 7) + ((n & 15) << 3) + (k & 7);
  hi[fo] = h;
  lo[fo] = __float2bfloat16(w - __bfloat162float(h));
}

__global__ __launch_bounds__(256)
void ax_build(const float* __restrict__ actions, const float* __restrict__ xs,
              bf16* __restrict__ dst) {
  const int idx = blockIdx.x * 256 + threadIdx.x;
  if (idx >= E_ * TB_ * 192) return;
  const int k = idx % 192;
  const int r = (idx / 192) % TB_;
  const int e = idx / (192 * TB_);
  float v = 0.f;
  if (k < 32) v = actions[((size_t)e * TB_ + r) * A_ + k];
  else if (k < 160) v = xs[((size_t)e * TB_ + r) * D_ + (k - 32)];
  dst[idx] = __float2bfloat16(v);
}

__global__ __launch_bounds__(256)
void waxT_build(const float* __restrict__ act_w, bf16* __restrict__ dst) {
  const int idx = blockIdx.x * 256 + threadIdx.x;
  if (idx >= E_ * 256 * 192) return;
  const int k = idx % 192;
  const int n = (idx / 192) % 256;
  const int e = idx / (192 * 256);
  float v = (k < 160) ? act_w[(size_t)e * 416 * 256 + (size_t)(256 + k) * 256 + n] : 0.f;
  dst[idx] = __float2bfloat16(v);
}

__global__ __launch_bounds__(256)
void gpack_build(const float* __restrict__ gw1, const float* __restrict__ gb1,
                 const float* __restrict__ gw2, _Float16* __restrict__ dst) {
  const int idx = blockIdx.x * 256 + threadIdx.x;
  if (idx >= 256 * 3 * 1024) return;
  const int l = idx / 3072, rem = idx - l * 3072, arr = rem >> 10, h = rem & 1023;
  const float* s = arr == 0 ? gw1 : (arr == 1 ? gb1 : gw2);
  dst[idx] = (_Float16)s[(size_t)l * 1024 + h];
}

// ---------------- q/KL device body (+z0 split hi/lo) ----------------
__device__ void qkl_dev(char* Ubuf, int e, int r0,
                        const float* ctx, int rows, int row_off, int ctx_estride,
                        const float* qw, const float* qb, const float* pm,
                        const float* pl, const float* eps0,
                        bf16* z0hi, bf16* z0lo, float* logqp, int tid) {
  float (*cx)[128] = (float(*)[128])Ubuf;
  float* red = (float*)(Ubuf + 16 * 128 * 4);
  {
    const int r = tid >> 4, c = (tid & 15) * 8;
    float4 v0 = make_float4(0.f, 0.f, 0.f, 0.f), v1 = v0;
    if (r0 + r < rows) {
      const float* src = ctx + (size_t)e * ctx_estride + (size_t)(r0 + r) * C_ + c;
      v0 = *(const float4*)src;
      v1 = *(const float4*)(src + 4);
    }
    *(float4*)&cx[r][c] = v0;
    *(float4*)&cx[r][c + 4] = v1;
  }
  if (tid < 16) red[tid] = 0.f;
  __syncthreads();
  const int j = tid;
  const float* w = qw + (size_t)e * C_ * 512;
  float am_[16] = {};
  float al_[16] = {};
  for (int k0 = 0; k0 < C_; k0 += 4) {
    float wm[4], wl[4];
#pragma unroll
    for (int q = 0; q < 4; ++q) {
      wm[q] = w[(size_t)(k0 + q) * 512 + j];
      wl[q] = w[(size_t)(k0 + q) * 512 + 256 + j];
    }
#pragma unroll
    for (int r = 0; r < 16; ++r) {
      const float4 cv = *(const float4*)&cx[r][k0];
      const float cc[4] = {cv.x, cv.y, cv.z, cv.w};
#pragma unroll
      for (int q = 0; q < 4; ++q) {
        am_[r] = fmaf(cc[q], wm[q], am_[r]);
        al_[r] = fmaf(cc[q], wl[q], al_[r]);
      }
    }
  }
  const float qbm = qb[(size_t)e * 512 + j];
  const float qbl = qb[(size_t)e * 512 + 256 + j];
  const float pmv = pm[(size_t)e * L_ + j];
  const float plv = pl[(size_t)e * L_ + j];
  const float inv2e = 0.5f * expf(-2.f * plv);
#pragma unroll
  for (int r = 0; r < 16; ++r) {
    float kl = 0.f;
    if (r0 + r < rows) {
      const float qm_ = am_[r] + qbm;
      const float ql_ = al_[r] + qbl;
      const float dm = qm_ - pmv;
      kl = plv - ql_ + (expf(2.f * ql_) + dm * dm) * inv2e - 0.5f;
      const int gi = row_off + r0 + r;
      if (gi < B_) {
        const size_t zi = ((size_t)e * B_ + gi) * L_ + j;
        const float z0 = qm_ + expf(ql_) * eps0[zi];
        const bf16 h = __float2bfloat16(z0);
        z0hi[zi] = h;
        z0lo[zi] = __float2bfloat16(z0 - __bfloat162float(h));
      }
    }
    for (int off = 32; off; off >>= 1) kl += __shfl_xor(kl, off, 64);
    if ((tid & 63) == 0) atomicAdd(&red[r], kl);
  }
  __syncthreads();
  if (tid < 16 && r0 + tid < rows) atomicAdd(&logqp[e], red[tid] * (1.0f / B_));
}

__global__ __launch_bounds__(256)
void qkl_kernel(const float* ctx, int rows, int row_off, int ctx_estride,
                const float* qw, const float* qb, const float* pm, const float* pl,
                const float* eps0, bf16* z0hi, bf16* z0lo, float* logqp) {
  __shared__ char U[16 * 128 * 4 + 64];
  qkl_dev(U, blockIdx.y, blockIdx.x * 16, ctx, rows, row_off, ctx_estride,
          qw, qb, pm, pl, eps0, z0hi, z0lo, logqp, threadIdx.x);
}

// ---------------- scan step kernels ----------------
// K1: act main (y<2) ; y==2: proj3(t-2) side.  grid (4, 3, 7)
__global__ __launch_bounds__(256, 2)
void k1_act(const bf16* __restrict__ zhi, const bf16* __restrict__ zlo,
            const bf16* __restrict__ wzh, const bf16* __restrict__ wzl,
            const float* __restrict__ axw, float* __restrict__ zP,
            bf16* __restrict__ zPb,
            const bf16* __restrict__ pbuf2, const bf16* __restrict__ pw3f,
            const float* __restrict__ proj_b3, float* __restrict__ pred, int t) {
  __shared__ short U[16 * 1024];
  const int tid = threadIdx.x;
  if (blockIdx.y == 2) {  // proj3 side for tp = t-2
    if (t < 2) return;
    const int tp = t - 2, rt = blockIdx.x, e = blockIdx.z;
    int nrows = 50 - rt * 16;
    if (nrows > 16) nrows = 16;
    tile_gemm(U, (const short*)pbuf2 + (size_t)(e * 50 + rt * 16) * 1024,
              nrows, 1024, 1024, (const short*)pw3f + (size_t)e * 131072, 0,
              proj_b3 + (size_t)e * 128,
              pred + (size_t)e * 640000 + (size_t)(tp * 50 + rt * 16) * 128,
              nullptr, 128, 0, tid);
    return;
  }
  short* Ah = U;
  short* Al = U + 4096;
  const int e = blockIdx.z, rb = blockIdx.x, nb = blockIdx.y * 128;
  const int r0 = rb * 13;
  const int nrows = (50 - r0 < 13) ? (50 - r0) : 13;
  const int lane = tid & 63, wv = tid >> 6;
  const int l15 = lane & 15, l4 = lane >> 4;
  const short* zh = (const short*)zhi + (size_t)(e * 50 + r0) * 256;
  const short* zl = (const short*)zlo + (size_t)(e * 50 + r0) * 256;
#pragma unroll
  for (int i = 0; i < 2; ++i) {
    const int lin = tid + i * 256, row = lin >> 5, ck = lin & 31;
    s8v vh = {}, vl = {};
    if (row < nrows) {
      vh = *(const s8v*)(zh + row * 256 + ck * 8);
      vl = *(const s8v*)(zl + row * 256 + ck * 8);
    }
    *(s8v*)(Ah + row * 256 + lswz(row, ck)) = vh;
    *(s8v*)(Al + row * 256 + lswz(row, ck)) = vl;
  }
  __syncthreads();
  const short* Bh = (const short*)wzh + (size_t)e * 65536;
  const short* Bl = (const short*)wzl + (size_t)e * 65536;
  f32x4 acc[2] = {};
#pragma unroll
  for (int kt = 0; kt < 8; ++kt) {
    const int ck = kt * 4 + l4;
    const s8v ah = *(const s8v*)(Ah + l15 * 256 + lswz(l15, ck));
    const s8v al = *(const s8v*)(Al + l15 * 256 + lswz(l15, ck));
#pragma unroll
    for (int nt = 0; nt < 2; ++nt) {
      const int ng = nb + wv * 32 + nt * 16;
      const size_t bo = ((size_t)(ng >> 4) * 8 + kt) * 512 + lane * 8;
      const s8v bh = *(const s8v*)(Bh + bo);
      const s8v bl = *(const s8v*)(Bl + bo);
      acc[nt] = MFMA(ah, bh, acc[nt], 0, 0, 0);
      acc[nt] = MFMA(al, bh, acc[nt], 0, 0, 0);
      acc[nt] = MFMA(ah, bl, acc[nt], 0, 0, 0);
    }
  }
#pragma unroll
  for (int nt = 0; nt < 2; ++nt) {
    const int col = nb + wv * 32 + nt * 16 + l15;
#pragma unroll
    for (int j = 0; j < 4; ++j) {
      const int row = l4 * 4 + j;
      if (row < nrows) {
        const int gr = e * 50 + r0 + row;
        const float v = acc[nt][j] + axw[((size_t)e * TB_ + t * 50 + r0 + row) * 256 + col];
        zP[(size_t)gr * 256 + col] = v;
        zPb[(size_t)gr * 256 + col] = __float2bfloat16(v);
      }
    }
  }
}

// K2: L1 main (y<16); side: encoder pipeline stage (t mod 4) of chunk (t/4).
// grid (22, 50)
__global__ __launch_bounds__(256, 2)
void k2_l1(const bf16* __restrict__ zPb, const bf16* __restrict__ w1f,
           const float* __restrict__ fb1, const float* __restrict__ hb1,
           bf16* __restrict__ fh1,
           const bf16* __restrict__ xs_bf,
           const bf16* __restrict__ ew1f, const float* __restrict__ enc_b1,
           bf16* __restrict__ ebuf1,
           const bf16* __restrict__ ew2f, const float* __restrict__ enc_b2,
           bf16* __restrict__ ebuf2,
           const bf16* __restrict__ ew3f, const float* __restrict__ enc_b3,
           float* __restrict__ ctxb,
           const float* __restrict__ qw, const float* __restrict__ qb,
           const float* __restrict__ pm, const float* __restrict__ pl,
           const float* __restrict__ eps0, bf16* __restrict__ zhi,
           bf16* __restrict__ zlo, float* __restrict__ logqp, int t) {
  __shared__ short U[16 * 1024];
  const int tid = threadIdx.x;
  const int x = blockIdx.x, y = blockIdx.y;
  if (y >= 16) {  // encoder side
    const int sid = (y - 16) * 22 + x;
    const int mode = t & 3, chunk = t >> 2;
    if (chunk >= 25) return;
    const int rowBase = 50 + chunk * MC;
    if (mode <= 1) {
      if (sid >= 728) return;
      const int e = sid / 104, rem = sid - e * 104, rt = rem >> 3, ntb = rem & 7;
      int nrows = MC - rt * 16;
      if (nrows > 16) nrows = 16;
      if (mode == 0) {
        tile_gemm(U, (const short*)xs_bf + (size_t)e * (TB_ * 128) +
                      (size_t)(rowBase + rt * 16) * 128,
                  nrows, 128, 128, (const short*)ew1f + (size_t)e * 131072, ntb * 8,
                  enc_b1 + (size_t)e * 1024, nullptr,
                  ebuf1 + (size_t)(e * MC + rt * 16) * 1024, 1024, 1, tid);
      } else {
        tile_gemm(U, (const short*)ebuf1 + (size_t)(e * MC + rt * 16) * 1024,
                  nrows, 1024, 1024, (const short*)ew2f + (size_t)e * 1048576, ntb * 8,
                  enc_b2 + (size_t)e * 1024, nullptr,
                  ebuf2 + (size_t)(e * MC + rt * 16) * 1024, 1024, 1, tid);
      }
    } else if (mode == 2) {
      if (sid >= 91) return;
      const int e = sid / 13, rt = sid - e * 13;
      int nrows = MC - rt * 16;
      if (nrows > 16) nrows = 16;
      tile_gemm(U, (const short*)ebuf2 + (size_t)(e * MC + rt * 16) * 1024,
                nrows, 1024, 1024, (const short*)ew3f + (size_t)e * 131072, 0,
                enc_b3 + (size_t)e * 128,
                ctxb + (size_t)(e * MC + rt * 16) * 128, nullptr, 128, 0, tid);
    } else {
      if (sid >= 91) return;
      const int e = sid / 13, rt = sid - e * 13;
      qkl_dev((char*)U, e, rt * 16, ctxb, MC, rowBase, MC * 128,
              qw, qb, pm, pl, eps0, zhi, zlo, logqp, tid);
    }
    return;
  }
  short* As = U;
  const int rb = x, nb = y * 128;
  const int r0 = rb * 16;
  const int lane = tid & 63, wv = tid >> 6;
  const int l15 = lane & 15, l4 = lane >> 4;
#pragma unroll
  for (int i = 0; i < 2; ++i) {
    const int lin = tid + i * 256, row = lin >> 5, ck = lin & 31;
    s8v v = {};
    if (r0 + row < EB_)
      v = *(const s8v*)((const short*)zPb + (size_t)(r0 + row) * 256 + ck * 8);
    *(s8v*)(As + row * 256 + lswz(row, ck)) = v;
  }
  __syncthreads();
  f32x4 acc[2] = {};
#pragma unroll
  for (int kt = 0; kt < 8; ++kt) {
    const int ck = kt * 4 + l4;
    const s8v a = *(const s8v*)(As + l15 * 256 + lswz(l15, ck));
#pragma unroll
    for (int nt = 0; nt < 2; ++nt) {
      const int ng = nb + wv * 32 + nt * 16;
      const s8v b = *(const s8v*)((const short*)w1f + ((size_t)(ng >> 4) * 8 + kt) * 512 + lane * 8);
      acc[nt] = MFMA(a, b, acc[nt], 0, 0, 0);
    }
  }
#pragma unroll
  for (int nt = 0; nt < 2; ++nt) {
    const int col = nb + wv * 32 + nt * 16 + l15;
    const float bv = (col < 1024) ? fb1[col] : hb1[col - 1024];
#pragma unroll
    for (int j = 0; j < 4; ++j) {
      const int row = r0 + l4 * 4 + j;
      if (row < EB_)
        fh1[(size_t)row * 2048 + col] = __float2bfloat16(fmaxf(acc[nt][j] + bv, 0.f));
    }
  }
}

// K3+G+P1: y<16 L2; y<20 g; y>=20 proj1(t-1).  grid (22, 31)
__global__ __launch_bounds__(256, 2)
void k3g(const bf16* __restrict__ fh1, const bf16* __restrict__ w2f,
         const float* __restrict__ fb2, const float* __restrict__ hb2,
         bf16* __restrict__ fh2, const float* __restrict__ zP,
         const _Float16* __restrict__ gpk, const float* __restrict__ gb2,
         float* __restrict__ gv,
         const bf16* __restrict__ zs_bf, const bf16* __restrict__ pw1f,
         const float* __restrict__ proj_b1, bf16* __restrict__ pbuf1, int t) {
  __shared__ short As[16 * 1024];
  const int rb = blockIdx.x, nbl = blockIdx.y;
  const int tid = threadIdx.x, lane = tid & 63, wv = tid >> 6;
  const int l15 = lane & 15, l4 = lane >> 4;
  const int r0 = rb * 16;
  if (nbl >= 20) {  // proj1 side for tp = t-1
    if (t < 1) return;
    const int sid = (nbl - 20) * 22 + rb;
    if (sid >= 224) return;
    const int e = sid / 32, rem = sid - e * 32, rt = rem >> 3, ntb = rem & 7;
    int nrows = 50 - rt * 16;
    if (nrows > 16) nrows = 16;
    tile_gemm(As, (const short*)zs_bf + (size_t)e * (TB_ * 256) +
                  (size_t)((t - 1) * 50 + rt * 16) * 256,
              nrows, 256, 256, (const short*)pw1f + (size_t)e * 262144, ntb * 8,
              proj_b1 + (size_t)e * 1024, nullptr,
              pbuf1 + (size_t)(e * 50 + rt * 16) * 1024, 1024, 2, tid);
    return;
  }
  if (nbl >= 16) {  // g block (validated round 14)
    float* ztile = (float*)As;
    const int c0 = (nbl - 16) * 64;
#pragma unroll
    for (int i = 0; i < 4; ++i) {
      const int lin = tid + i * 256, row = lin >> 6, col = lin & 63;
      ztile[row * 64 + col] =
          (r0 + row < EB_) ? zP[(size_t)(r0 + row) * 256 + c0 + col] : 1.0f;
    }
    __syncthreads();
    const int lloc = tid >> 2, hq = tid & 3;
    const _Float16* gl = gpk + (size_t)(c0 + lloc) * 3072 + hq * 256;
    f16x2 z2[16];
#pragma unroll
    for (int r = 0; r < 16; ++r) {
      const _Float16 zh_ = (_Float16)ztile[r * 64 + lloc];
      z2[r] = f16x2{zh_, zh_};
    }
    float ga[16] = {};
    for (int hp = 0; hp < 128; ++hp) {
      const f16x2 w1v = *(const f16x2*)(gl + 2 * hp);
      const f16x2 b1v = *(const f16x2*)(gl + 1024 + 2 * hp);
      const f16x2 w2v = *(const f16x2*)(gl + 2048 + 2 * hp);
#pragma unroll
      for (int r = 0; r < 16; ++r) {
        f16x2 tt = z2[r] * w1v + b1v;
#if __has_builtin(__builtin_elementwise_max)
        const f16x2 zz = {};
        tt = __builtin_elementwise_max(tt, zz);
#else
        tt[0] = tt[0] > (_Float16)0 ? tt[0] : (_Float16)0;
        tt[1] = tt[1] > (_Float16)0 ? tt[1] : (_Float16)0;
#endif
#if __has_builtin(__builtin_amdgcn_fdot2)
        ga[r] = __builtin_amdgcn_fdot2(tt, w2v, ga[r], false);
#else
        ga[r] += (float)tt[0] * (float)w2v[0] + (float)tt[1] * (float)w2v[1];
#endif
      }
    }
#pragma unroll
    for (int r = 0; r < 16; ++r) {
      float v = ga[r];
      v += __shfl_xor(v, 1, 64);
      v += __shfl_xor(v, 2, 64);
      if (hq == 0 && r0 + r < EB_)
        gv[(size_t)(r0 + r) * 256 + c0 + lloc] = v + gb2[c0 + lloc];
    }
    return;
  }
  // L2 block (round-6 verbatim)
  const int nb = nbl * 128;
  const int half = (nbl >= 8) ? 1024 : 0;
#pragma unroll
  for (int i = 0; i < 8; ++i) {
    const int lin = tid + i * 256, row = lin >> 7, ck = lin & 127;
    s8v v = {};
    if (r0 + row < EB_)
      v = *(const s8v*)((const short*)fh1 + (size_t)(r0 + row) * 2048 + half + ck * 8);
    *(s8v*)(As + row * 1024 + lswz(row, ck)) = v;
  }
  __syncthreads();
  f32x4 acc[2] = {};
#pragma unroll 4
  for (int kt = 0; kt < 32; ++kt) {
    const int ck = kt * 4 + l4;
    const s8v a = *(const s8v*)(As + l15 * 1024 + lswz(l15, ck));
#pragma unroll
    for (int nt = 0; nt < 2; ++nt) {
      const int ng = nb + wv * 32 + nt * 16;
      const s8v b = *(const s8v*)((const short*)w2f + ((size_t)(ng >> 4) * 32 + kt) * 512 + lane * 8);
      acc[nt] = MFMA(a, b, acc[nt], 0, 0, 0);
    }
  }
#pragma unroll
  for (int nt = 0; nt < 2; ++nt) {
    const int col = nb + wv * 32 + nt * 16 + l15;
    const float bv = half ? hb2[col - 1024] : fb2[col];
#pragma unroll
    for (int j = 0; j < 4; ++j) {
      const int row = r0 + l4 * 4 + j;
      if (row < EB_)
        fh2[(size_t)row * 2048 + col] = __float2bfloat16(tanhf(acc[nt][j] + bv));
    }
  }
}

// K4+P2: main y<4; side proj2(t-1) y>=4.  grid (22, 15)
__global__ __launch_bounds__(256, 1)
void k4_fin(const bf16* __restrict__ fh2, const bf16* __restrict__ w3f,
            const float* __restrict__ fb3, const float* __restrict__ hb3,
            const float* __restrict__ gv, const float* __restrict__ zP,
            const float* __restrict__ dw, bf16* __restrict__ zhi,
            bf16* __restrict__ zlo, bf16* __restrict__ zs_bf,
            float* __restrict__ logqp,
            const bf16* __restrict__ pbuf1, const bf16* __restrict__ pw2f,
            const float* __restrict__ proj_b2, bf16* __restrict__ pbuf2, int t) {
  __shared__ short As[16 * 1024];
  __shared__ float ztile[16][64];
  __shared__ float ebuck[8];
  const int tid = threadIdx.x, lane = tid & 63, wv = tid >> 6;
  const int l15 = lane & 15, l4 = lane >> 4;
  if (blockIdx.y >= 4) {  // proj2 side for tp = t-1
    if (t < 1) return;
    const int sid = (blockIdx.y - 4) * 22 + blockIdx.x;
    if (sid >= 224) return;
    const int e = sid / 32, rem = sid - e * 32, rt = rem >> 3, ntb = rem & 7;
    int nrows = 50 - rt * 16;
    if (nrows > 16) nrows = 16;
    tile_gemm(As, (const short*)pbuf1 + (size_t)(e * 50 + rt * 16) * 1024,
              nrows, 1024, 1024, (const short*)pw2f + (size_t)e * 1048576, ntb * 8,
              proj_b2 + (size_t)e * 1024, nullptr,
              pbuf2 + (size_t)(e * 50 + rt * 16) * 1024, 1024, 2, tid);
    return;
  }
  const int rb = blockIdx.x, cb = blockIdx.y;
  const int r0 = rb * 16, c0 = cb * 64;
  if (tid < 8) ebuck[tid] = 0.f;
#pragma unroll
  for (int i = 0; i < 4; ++i) {
    const int lin = tid + i * 256, row = lin >> 6, col = lin & 63;
    ztile[row][col] = (r0 + row < EB_) ? zP[(size_t)(r0 + row) * 256 + c0 + col] : 1.0f;
  }
  f32x4 accF = {}, accH = {};
#pragma unroll
  for (int fb = 0; fb < 2; ++fb) {
    __syncthreads();
#pragma unroll
    for (int i = 0; i < 8; ++i) {
      const int lin = tid + i * 256, row = lin >> 7, ck = lin & 127;
      s8v v = {};
      if (r0 + row < EB_)
        v = *(const s8v*)((const short*)fh2 + (size_t)(r0 + row) * 2048 + fb * 1024 + ck * 8);
      *(s8v*)(As + row * 1024 + lswz(row, ck)) = v;
    }
    __syncthreads();
    const int ng = fb * 256 + c0 + wv * 16;
    f32x4 acc = {};
#pragma unroll 4
    for (int kt = 0; kt < 32; ++kt) {
      const int ck = kt * 4 + l4;
      const s8v a = *(const s8v*)(As + l15 * 1024 + lswz(l15, ck));
      const s8v b = *(const s8v*)((const short*)w3f + ((size_t)(ng >> 4) * 32 + kt) * 512 + lane * 8);
      acc = MFMA(a, b, acc, 0, 0, 0);
    }
    if (fb) accH = acc; else accF = acc;
  }
  __syncthreads();
  const int col_loc = wv * 16 + l15, col = c0 + col_loc;
  const float fb3v = fb3[col], hb3v = hb3[col];
#pragma unroll
  for (int j = 0; j < 4; ++j) {
    const int rl = l4 * 4 + j, row = r0 + rl;
    if (row < EB_) {
      const float fv = accF[j] + fb3v;
      const float hv = accH[j] + hb3v;
      const float gvv = gv[(size_t)row * 256 + col];
      const float u = (fv - hv) / gvv;
      atomicAdd(&ebuck[row / 50], 0.001f * u * u);
      const float znew = ztile[rl][col_loc] + 0.1f * fv +
                         gvv * (SQRTH * dw[(size_t)t * (EB_ * 256) + (size_t)row * 256 + col]);
      const bf16 h = __float2bfloat16(znew);
      const size_t zi = (size_t)row * 256 + col;
      zhi[zi] = h;
      zlo[zi] = __float2bfloat16(znew - __bfloat162float(h));
      const int e = row / 50, b = row - e * 50;
      zs_bf[((size_t)e * TB_ + t * 50 + b) * 256 + col] = h;
    }
  }
  __syncthreads();
  if (tid < 7) {
    const float v = ebuck[tid];
    if (v != 0.f) atomicAdd(&logqp[tid], v);
  }
}

__global__ void init_kernel(float* logqp) {
  if (threadIdx.x < E_) logqp[threadIdx.x] = 0.f;
}

extern "C" void kernel_launch(void* const* d_in, const int* in_sizes, int n_in,
                              void* d_out, int out_size, void* d_ws, size_t ws_size,
                              hipStream_t stream) {
  (void)in_sizes; (void)n_in; (void)out_size; (void)ws_size;
  const float* enc_w1 = (const float*)d_in[0];
  const float* enc_b1 = (const float*)d_in[1];
  const float* enc_w2 = (const float*)d_in[2];
  const float* enc_b2 = (const float*)d_in[3];
  const float* enc_w3 = (const float*)d_in[4];
  const float* enc_b3 = (const float*)d_in[5];
  const float* qz0_w  = (const float*)d_in[6];
  const float* qz0_b  = (const float*)d_in[7];
  const float* act_w  = (const float*)d_in[8];
  const float* act_b  = (const float*)d_in[9];
  const float* proj_w1 = (const float*)d_in[10];
  const float* proj_b1 = (const float*)d_in[11];
  const float* proj_w2 = (const float*)d_in[12];
  const float* proj_b2 = (const float*)d_in[13];
  const float* proj_w3 = (const float*)d_in[14];
  const float* proj_b3 = (const float*)d_in[15];
  const float* f_w1 = (const float*)d_in[16];
  const float* f_b1 = (const float*)d_in[17];
  const float* f_w2 = (const float*)d_in[18];
  const float* f_b2 = (const float*)d_in[19];
  const float* f_w3 = (const float*)d_in[20];
  const float* f_b3 = (const float*)d_in[21];
  const float* h_w1 = (const float*)d_in[22];
  const float* h_b1 = (const float*)d_in[23];
  const float* h_w2 = (const float*)d_in[24];
  const float* h_b2 = (const float*)d_in[25];
  const float* h_w3 = (const float*)d_in[26];
  const float* h_b3 = (const float*)d_in[27];
  const float* g_w1 = (const float*)d_in[28];
  const float* g_b1 = (const float*)d_in[29];
  const float* g_w2 = (const float*)d_in[30];
  const float* g_b2 = (const float*)d_in[31];
  const float* pz0_mean   = (const float*)d_in[32];
  const float* pz0_logstd = (const float*)d_in[33];
  const float* xs      = (const float*)d_in[34];
  const float* actions = (const float*)d_in[35];
  const float* eps_z0  = (const float*)d_in[36];
  const float* dw      = (const float*)d_in[37];

  float* out = (float*)d_out;
  float* logqp = out;
  float* pred = out + E_;

  char* base = (char*)d_ws;
  size_t off = 0;
  auto alloc = [&](size_t bytes) {
    void* p = base + off;
    off = (off + bytes + 255) & ~(size_t)255;
    return p;
  };
  bf16* zhi    = (bf16*)alloc((size_t)EB_ * 256 * 2);
  bf16* zlo    = (bf16*)alloc((size_t)EB_ * 256 * 2);
  float* zP    = (float*)alloc((size_t)EB_ * 256 * 4);
  bf16* zPb    = (bf16*)alloc((size_t)EB_ * 256 * 2);
  bf16* fh1    = (bf16*)alloc((size_t)EB_ * 2048 * 2);
  bf16* fh2    = (bf16*)alloc((size_t)EB_ * 2048 * 2);
  float* gvb   = (float*)alloc((size_t)EB_ * 256 * 4);
  bf16* zs_bf  = (bf16*)alloc((size_t)E_ * T_ * B_ * 256 * 2);
  float* axw   = (float*)alloc((size_t)E_ * TB_ * 256 * 4);
  bf16* ax_bf  = (bf16*)alloc((size_t)E_ * TB_ * 192 * 2);
  bf16* waxT   = (bf16*)alloc((size_t)E_ * 256 * 192 * 2);
  bf16* wzh    = (bf16*)alloc((size_t)E_ * 65536 * 2);
  bf16* wzl    = (bf16*)alloc((size_t)E_ * 65536 * 2);
  bf16* w1f    = (bf16*)alloc((size_t)2048 * 256 * 2);
  bf16* w2f    = (bf16*)alloc((size_t)2048 * 1024 * 2);
  bf16* w3f    = (bf16*)alloc((size_t)512 * 1024 * 2);
  _Float16* gpk = (_Float16*)alloc((size_t)256 * 3 * 1024 * 2);
  bf16* xs_bf  = (bf16*)alloc((size_t)E_ * TB_ * D_ * 2);
  bf16* ew1f = (bf16*)alloc((size_t)E_ * 131072 * 2);
  bf16* ew2f = (bf16*)alloc((size_t)E_ * 1048576 * 2);
  bf16* ew3f = (bf16*)alloc((size_t)E_ * 131072 * 2);
  bf16* pw1f = (bf16*)alloc((size_t)E_ * 262144 * 2);
  bf16* pw2f = (bf16*)alloc((size_t)E_ * 1048576 * 2);
  bf16* pw3f = (bf16*)alloc((size_t)E_ * 131072 * 2);
  bf16* ebuf1 = (bf16*)alloc((size_t)E_ * MC * 1024 * 2);
  bf16* ebuf2 = (bf16*)alloc((size_t)E_ * MC * 1024 * 2);
  float* ctxb = (float*)alloc((size_t)E_ * MC * 128 * 4);
  bf16* bb1   = (bf16*)alloc((size_t)E_ * 50 * 1024 * 2);
  bf16* bb2   = (bf16*)alloc((size_t)E_ * 50 * 1024 * 2);
  float* ctx0 = (float*)alloc((size_t)E_ * 50 * 128 * 4);
  bf16* pbuf1 = (bf16*)alloc((size_t)350 * 1024 * 2);
  bf16* pbuf2 = (bf16*)alloc((size_t)350 * 1024 * 2);

  init_kernel<<<dim3(1), dim3(64), 0, stream>>>(logqp);

  const dim3 cb256(256);
  cvt_kernel<<<dim3((E_ * TB_ * D_ / 4 + 255) / 256), cb256, 0, stream>>>(xs, xs_bf, E_ * TB_ * D_ / 4);
  ax_build<<<dim3((E_ * TB_ * 192 + 255) / 256), cb256, 0, stream>>>(actions, xs, ax_bf);
  waxT_build<<<dim3((E_ * 256 * 192 + 255) / 256), cb256, 0, stream>>>(act_w, waxT);
  packWz<<<dim3((E_ * 65536 + 255) / 256), cb256, 0, stream>>>(act_w, wzh, wzl);
  packW<<<dim3((256 * 1024 + 255) / 256), cb256, 0, stream>>>(f_w1, w1f, 256, 1024);
  packW<<<dim3((256 * 1024 + 255) / 256), cb256, 0, stream>>>(h_w1, w1f + (size_t)1024 * 256, 256, 1024);
  packW<<<dim3((1024 * 1024 + 255) / 256), cb256, 0, stream>>>(f_w2, w2f, 1024, 1024);
  packW<<<dim3((1024 * 1024 + 255) / 256), cb256, 0, stream>>>(h_w2, w2f + (size_t)1024 * 1024, 1024, 1024);
  packW<<<dim3((1024 * 256 + 255) / 256), cb256, 0, stream>>>(f_w3, w3f, 1024, 256);
  packW<<<dim3((1024 * 256 + 255) / 256), cb256, 0, stream>>>(h_w3, w3f + (size_t)256 * 1024, 1024, 256);
  gpack_build<<<dim3((256 * 3 * 1024 + 255) / 256), cb256, 0, stream>>>(g_w1, g_b1, g_w2, gpk);
  packWE<<<dim3(512, 1, E_), cb256, 0, stream>>>(enc_w1, ew1f, 128, 1024, 131072, 131072);
  packWE<<<dim3(4096, 1, E_), cb256, 0, stream>>>(enc_w2, ew2f, 1024, 1024, 1048576, 1048576);
  packWE<<<dim3(512, 1, E_), cb256, 0, stream>>>(enc_w3, ew3f, 1024, 128, 131072, 131072);
  packWE<<<dim3(1024, 1, E_), cb256, 0, stream>>>(proj_w1, pw1f, 256, 1024, 262144, 262144);
  packWE<<<dim3(4096, 1, E_), cb256, 0, stream>>>(proj_w2, pw2f, 1024, 1024, 1048576, 1048576);
  packWE<<<dim3(512, 1, E_), cb256, 0, stream>>>(proj_w3, pw3f, 1024, 128, 131072, 131072);

  BG g;
  for (int e = 0; e < E_; ++e) {
    g.A[e] = ax_bf + (size_t)e * TB_ * 192;
    g.W[e] = waxT + (size_t)e * 256 * 192;
    g.bias[e] = act_b + (size_t)e * 256;
    g.Cf[e] = axw + (size_t)e * TB_ * 256;
  }
  bgemm<128, 0, 0><<<dim3((TB_ + 127) / 128, 2, E_), 256, 0, stream>>>(g, TB_, 192, 192, 192, 256);

  // ---- bootstrap: encoder rows 0..49 per e -> z0 (+ their KL) ----
  sgemm_e<<<dim3(4, 8, E_), cb256, 0, stream>>>(
      xs_bf, (long)TB_ * 128, 0, 128, 50, ew1f, 131072, 128, enc_b1, 1024,
      nullptr, bb1, 51200, 0, 1024, 1);
  sgemm_e<<<dim3(4, 8, E_), cb256, 0, stream>>>(
      bb1, 51200, 0, 1024, 50, ew2f, 1048576, 1024, enc_b2, 1024,
      nullptr, bb2, 51200, 0, 1024, 1);
  sgemm_e<<<dim3(4, 1, E_), cb256, 0, stream>>>(
      bb2, 51200, 0, 1024, 50, ew3f, 131072, 1024, enc_b3, 128,
      ctx0, nullptr, 6400, 0, 128, 0);
  qkl_kernel<<<dim3(4, E_), cb256, 0, stream>>>(
      ctx0, 50, 0, 6400, qz0_w, qz0_b, pz0_mean, pz0_logstd, eps_z0,
      zhi, zlo, logqp);

  // ---- Scan: 4 kernels/step with folded encoder + projector side work ----
  for (int t = 0; t < T_; ++t) {
    k1_act<<<dim3(4, 3, E_), cb256, 0, stream>>>(zhi, zlo, wzh, wzl, axw, zP, zPb,
                                                 pbuf2, pw3f, proj_b3, pred, t);
    k2_l1<<<dim3(22, 50), cb256, 0, stream>>>(zPb, w1f, f_b1, h_b1, fh1,
                                              xs_bf, ew1f, enc_b1, ebuf1,
                                              ew2f, enc_b2, ebuf2,
                                              ew3f, enc_b3, ctxb,
                                              qz0_w, qz0_b, pz0_mean, pz0_logstd,
                                              eps_z0, zhi, zlo, logqp, t);
    k3g<<<dim3(22, 31), cb256, 0, stream>>>(fh1, w2f, f_b2, h_b2, fh2,
                                            zP, gpk, g_b2, gvb,
                                            zs_bf, pw1f, proj_b1, pbuf1, t);
    k4_fin<<<dim3(22, 15), cb256, 0, stream>>>(fh2, w3f, f_b3, h_b3, gvb,
                                               zP, dw, zhi, zlo, zs_bf, logqp,
                                               pbuf1, pw2f, proj_b2, pbuf2, t);
  }

  // ---- post: finish projector for steps 98 (proj3) and 99 (proj1..3) ----
  sgemm_e<<<dim3(4, 1, E_), cb256, 0, stream>>>(
      pbuf2, 51200, 0, 1024, 50, pw3f, 131072, 1024, proj_b3, 128,
      pred, nullptr, 640000, (long)98 * 50 * 128, 128, 0);
  sgemm_e<<<dim3(4, 8, E_), cb256, 0, stream>>>(
      zs_bf, (long)TB_ * 256, (long)99 * 50 * 256, 256, 50, pw1f, 262144, 256,
      proj_b1, 1024, nullptr, pbuf1, 51200, 0, 1024, 2);
  sgemm_e<<<dim3(4, 8, E_), cb256, 0, stream>>>(
      pbuf1, 51200, 0, 1024, 50, pw2f, 1048576, 1024, proj_b2, 1024,
      nullptr, pbuf2, 51200, 0, 1024, 2);
  sgemm_e<<<dim3(4, 1, E_), cb256, 0, stream>>>(
      pbuf2, 51200, 0, 1024, 50, pw3f, 131072, 1024, proj_b3, 128,
      pred, nullptr, 640000, (long)99 * 50 * 128, 128, 0);
}

// Round 16
// 9905.367 us; speedup vs baseline: 1.1378x; 1.1378x over previous
//
#include <hip/hip_runtime.h>
#include <hip/hip_bf16.h>
#include <math.h>

#define E_ 7
#define B_ 50
#define T_ 100
#define D_ 128
#define A_ 32
#define L_ 256
#define H_ 1024
#define C_ 128
#define EB_ 350
#define TB_ 5000
#define SQRTH 0.31622776601683794f

typedef __attribute__((ext_vector_type(8))) short s8v;
typedef __attribute__((ext_vector_type(4))) float f32x4;
typedef _Float16 f16x2 __attribute__((ext_vector_type(2)));
typedef __hip_bfloat16 bf16;

#define MFMA __builtin_amdgcn_mfma_f32_16x16x32_bf16

__device__ __forceinline__ int lswz(int row, int ck) {
  return (((ck & ~7) | ((ck ^ row) & 7)) << 3);
}

struct BG {
  const bf16* A[8];
  const bf16* W[8];
  const float* bias[8];
  float* Cf[8];
  bf16* Cb[8];
};

// ---------------- bf16 MFMA GEMM (validated round 2) ----------------
template<int BM, int ACT, int OUT>
__global__ __launch_bounds__(256)
void bgemm(BG g, int M, int K, int lda, int ldw, int ldc) {
  __shared__ short As[BM * 64];
  __shared__ short Ws[128 * 64];
  const short* Ap = (const short*)g.A[blockIdx.z];
  const short* Wp = (const short*)g.W[blockIdx.z];
  const int bm = blockIdx.x * BM, bn = blockIdx.y * 128;
  const int tid = threadIdx.x;
  const int wv = tid >> 6, lane = tid & 63;
  const int wm0 = (wv >> 1) * (BM / 2), wn0 = (wv & 1) * 64;
  const int l15 = lane & 15, l4 = lane >> 4;
  constexpr int FM = BM / 32;
  constexpr int AI = BM / 32;
  f32x4 acc[FM][4] = {};
  for (int k0 = 0; k0 < K; k0 += 64) {
    s8v av[AI], wvv[4];
#pragma unroll
    for (int i = 0; i < AI; ++i) {
      const int c = tid + i * 256, r = c >> 3, ck = c & 7;
      s8v v = {};
      if (bm + r < M) v = *(const s8v*)(Ap + (size_t)(bm + r) * lda + k0 + ck * 8);
      av[i] = v;
    }
#pragma unroll
    for (int i = 0; i < 4; ++i) {
      const int c = tid + i * 256, r = c >> 3, ck = c & 7;
      wvv[i] = *(const s8v*)(Wp + (size_t)(bn + r) * ldw + k0 + ck * 8);
    }
    __syncthreads();
#pragma unroll
    for (int i = 0; i < AI; ++i) {
      const int c = tid + i * 256, r = c >> 3, ck = c & 7;
      *(s8v*)(As + r * 64 + ((ck ^ (r & 7)) << 3)) = av[i];
    }
#pragma unroll
    for (int i = 0; i < 4; ++i) {
      const int c = tid + i * 256, r = c >> 3, ck = c & 7;
      *(s8v*)(Ws + r * 64 + ((ck ^ (r & 7)) << 3)) = wvv[i];
    }
    __syncthreads();
#pragma unroll
    for (int ks = 0; ks < 2; ++ks) {
      s8v af[FM], bfr[4];
#pragma unroll
      for (int m = 0; m < FM; ++m) {
        const int r = wm0 + m * 16 + l15, ck = ks * 4 + l4;
        af[m] = *(const s8v*)(As + r * 64 + ((ck ^ (r & 7)) << 3));
      }
#pragma unroll
      for (int n = 0; n < 4; ++n) {
        const int r = wn0 + n * 16 + l15, ck = ks * 4 + l4;
        bfr[n] = *(const s8v*)(Ws + r * 64 + ((ck ^ (r & 7)) << 3));
      }
#pragma unroll
      for (int m = 0; m < FM; ++m)
#pragma unroll
        for (int n = 0; n < 4; ++n)
          acc[m][n] = MFMA(af[m], bfr[n], acc[m][n], 0, 0, 0);
    }
    __syncthreads();
  }
  const float* bias = g.bias[blockIdx.z];
  float* Cf = g.Cf[blockIdx.z];
  bf16* Cb = g.Cb[blockIdx.z];
#pragma unroll
  for (int n = 0; n < 4; ++n) {
    const int col = bn + wn0 + n * 16 + l15;
    const float bv = bias ? bias[col] : 0.f;
#pragma unroll
    for (int m = 0; m < FM; ++m) {
#pragma unroll
      for (int j = 0; j < 4; ++j) {
        const int row = bm + wm0 + m * 16 + l4 * 4 + j;
        if (row < M) {
          float v = acc[m][n][j] + bv;
          if (ACT == 1) v = fmaxf(v, 0.f);
          if (ACT == 2) v = tanhf(v);
          if (OUT == 0) Cf[(size_t)row * ldc + col] = v;
          if (OUT == 1) Cb[(size_t)row * ldc + col] = __float2bfloat16(v);
        }
      }
    }
  }
}

// ---------------- conversions / packing (validated round 6) ----------------
__global__ __launch_bounds__(256)
void cvtT_kernel(const float* __restrict__ src, bf16* __restrict__ dst,
                 int K, int N, long ss, long ds) {
  __shared__ float t[32][33];
  src += (size_t)blockIdx.z * ss;
  dst += (size_t)blockIdx.z * ds;
  const int n0 = blockIdx.x * 32, k0 = blockIdx.y * 32;
  const int tx = threadIdx.x & 31, ty = threadIdx.x >> 5;
#pragma unroll
  for (int i = 0; i < 4; ++i)
    t[ty + 8 * i][tx] = src[(size_t)(k0 + ty + 8 * i) * N + n0 + tx];
  __syncthreads();
#pragma unroll
  for (int i = 0; i < 4; ++i)
    dst[(size_t)(n0 + ty + 8 * i) * K + k0 + tx] = __float2bfloat16(t[tx][ty + 8 * i]);
}

struct B4 { bf16 a, b, c, d; };
__global__ __launch_bounds__(256)
void cvt_kernel(const float* __restrict__ s, bf16* __restrict__ d, int n4) {
  const int i = blockIdx.x * 256 + threadIdx.x;
  if (i < n4) {
    const float4 v = ((const float4*)s)[i];
    B4 o = {__float2bfloat16(v.x), __float2bfloat16(v.y),
            __float2bfloat16(v.z), __float2bfloat16(v.w)};
    ((B4*)d)[i] = o;
  }
}

__global__ __launch_bounds__(256)
void packW(const float* __restrict__ src, bf16* __restrict__ dst, int K, int N) {
  const int idx = blockIdx.x * 256 + threadIdx.x;
  if (idx >= K * N) return;
  const int k = idx / N, n = idx - k * N;
  const size_t fo = ((size_t)(n >> 4) * (K >> 5) + (k >> 5)) * 512 +
                    (((k >> 3) & 3) << 7) + ((n & 15) << 3) + (k & 7);
  dst[fo] = __float2bfloat16(src[idx]);
}

__global__ __launch_bounds__(256)
void packWz(const float* __restrict__ act_w, bf16* __restrict__ hi, bf16* __restrict__ lo) {
  const int idx = blockIdx.x * 256 + threadIdx.x;
  if (idx >= E_ * 65536) return;
  const int e = idx >> 16, rem = idx & 65535, k = rem >> 8, n = rem & 255;
  const float w = act_w[(size_t)e * 416 * 256 + (size_t)k * 256 + n];
  const bf16 h = __float2bfloat16(w);
  const size_t fo = (size_t)e * 65536 + ((size_t)(n >> 4) * 8 + (k >> 5)) * 512 +
                    (((k >> 3) & 3) << 7) + ((n & 15) << 3) + (k & 7);
  hi[fo] = h;
  lo[fo] = __float2bfloat16(w - __bfloat162float(h));
}

__global__ __launch_bounds__(256)
void ax_build(const float* __restrict__ actions, const float* __restrict__ xs,
              bf16* __restrict__ dst) {
  const int idx = blockIdx.x * 256 + threadIdx.x;
  if (idx >= E_ * TB_ * 192) return;
  const int k = idx % 192;
  const int r = (idx / 192) % TB_;
  const int e = idx / (192 * TB_);
  float v = 0.f;
  if (k < 32) v = actions[((size_t)e * TB_ + r) * A_ + k];
  else if (k < 160) v = xs[((size_t)e * TB_ + r) * D_ + (k - 32)];
  dst[idx] = __float2bfloat16(v);
}

__global__ __launch_bounds__(256)
void waxT_build(const float* __restrict__ act_w, bf16* __restrict__ dst) {
  const int idx = blockIdx.x * 256 + threadIdx.x;
  if (idx >= E_ * 256 * 192) return;
  const int k = idx % 192;
  const int n = (idx / 192) % 256;
  const int e = idx / (192 * 256);
  float v = (k < 160) ? act_w[(size_t)e * 416 * 256 + (size_t)(256 + k) * 256 + n] : 0.f;
  dst[idx] = __float2bfloat16(v);
}

__global__ __launch_bounds__(256)
void gpack_build(const float* __restrict__ gw1, const float* __restrict__ gb1,
                 const float* __restrict__ gw2, _Float16* __restrict__ dst) {
  const int idx = blockIdx.x * 256 + threadIdx.x;
  if (idx >= 256 * 3 * 1024) return;
  const int l = idx / 3072, rem = idx - l * 3072, arr = rem >> 10, h = rem & 1023;
  const float* s = arr == 0 ? gw1 : (arr == 1 ? gb1 : gw2);
  dst[idx] = (_Float16)s[(size_t)l * 1024 + h];
}

// ---------------- q/KL (+z0 split hi/lo) ----------------
__global__ __launch_bounds__(256)
void qkl_kernel(const float* __restrict__ ctx, int rows, int row_off, int ctx_estride,
                const float* __restrict__ qw, const float* __restrict__ qb,
                const float* __restrict__ pm, const float* __restrict__ pl,
                const float* __restrict__ eps0, bf16* __restrict__ z0hi,
                bf16* __restrict__ z0lo, float* __restrict__ logqp) {
  __shared__ float cx[16][128];
  __shared__ float red[16];
  const int e = blockIdx.y;
  const int r0 = blockIdx.x * 16;
  const int tid = threadIdx.x;
  {
    const int r = tid >> 4, c = (tid & 15) * 8;
    float4 v0 = make_float4(0.f, 0.f, 0.f, 0.f), v1 = v0;
    if (r0 + r < rows) {
      const float* src = ctx + (size_t)e * ctx_estride + (size_t)(r0 + r) * C_ + c;
      v0 = *(const float4*)src;
      v1 = *(const float4*)(src + 4);
    }
    *(float4*)&cx[r][c] = v0;
    *(float4*)&cx[r][c + 4] = v1;
  }
  if (tid < 16) red[tid] = 0.f;
  __syncthreads();
  const int j = tid;
  const float* w = qw + (size_t)e * C_ * 512;
  float am_[16] = {};
  float al_[16] = {};
  for (int k0 = 0; k0 < C_; k0 += 4) {
    float wm[4], wl[4];
#pragma unroll
    for (int q = 0; q < 4; ++q) {
      wm[q] = w[(size_t)(k0 + q) * 512 + j];
      wl[q] = w[(size_t)(k0 + q) * 512 + 256 + j];
    }
#pragma unroll
    for (int r = 0; r < 16; ++r) {
      const float4 cv = *(const float4*)&cx[r][k0];
      const float cc[4] = {cv.x, cv.y, cv.z, cv.w};
#pragma unroll
      for (int q = 0; q < 4; ++q) {
        am_[r] = fmaf(cc[q], wm[q], am_[r]);
        al_[r] = fmaf(cc[q], wl[q], al_[r]);
      }
    }
  }
  const float qbm = qb[(size_t)e * 512 + j];
  const float qbl = qb[(size_t)e * 512 + 256 + j];
  const float pmv = pm[(size_t)e * L_ + j];
  const float plv = pl[(size_t)e * L_ + j];
  const float inv2e = 0.5f * expf(-2.f * plv);
#pragma unroll
  for (int r = 0; r < 16; ++r) {
    float kl = 0.f;
    if (r0 + r < rows) {
      const float qm_ = am_[r] + qbm;
      const float ql_ = al_[r] + qbl;
      const float dm = qm_ - pmv;
      kl = plv - ql_ + (expf(2.f * ql_) + dm * dm) * inv2e - 0.5f;
      const int gi = row_off + r0 + r;
      if (gi < B_) {  // t == 0 rows -> z0
        const size_t zi = ((size_t)e * B_ + gi) * L_ + j;
        const float z0 = qm_ + expf(ql_) * eps0[zi];
        const bf16 h = __float2bfloat16(z0);
        z0hi[zi] = h;
        z0lo[zi] = __float2bfloat16(z0 - __bfloat162float(h));
      }
    }
    for (int off = 32; off; off >>= 1) kl += __shfl_xor(kl, off, 64);
    if ((tid & 63) == 0) atomicAdd(&red[r], kl);
  }
  __syncthreads();
  if (tid < 16 && r0 + tid < rows) atomicAdd(&logqp[e], red[tid] * (1.0f / B_));
}

// ---------------- scan step kernels ----------------
// K1: zP = (zhi+zlo) @ Wz(hi/lo) + axw[t].  grid (4 rb13, 2 nt128, 7 e)
__global__ __launch_bounds__(256, 2)
void k1_act(const bf16* __restrict__ zhi, const bf16* __restrict__ zlo,
            const bf16* __restrict__ wzh, const bf16* __restrict__ wzl,
            const float* __restrict__ axw, float* __restrict__ zP,
            bf16* __restrict__ zPb, int t) {
  __shared__ short Ah[16 * 256];
  __shared__ short Al[16 * 256];
  const int e = blockIdx.z, rb = blockIdx.x, nb = blockIdx.y * 128;
  const int r0 = rb * 13;
  const int nrows = (50 - r0 < 13) ? (50 - r0) : 13;
  const int tid = threadIdx.x, lane = tid & 63, wv = tid >> 6;
  const int l15 = lane & 15, l4 = lane >> 4;
  const short* zh = (const short*)zhi + (size_t)(e * 50 + r0) * 256;
  const short* zl = (const short*)zlo + (size_t)(e * 50 + r0) * 256;
#pragma unroll
  for (int i = 0; i < 2; ++i) {
    const int lin = tid + i * 256, row = lin >> 5, ck = lin & 31;
    s8v vh = {}, vl = {};
    if (row < nrows) {
      vh = *(const s8v*)(zh + row * 256 + ck * 8);
      vl = *(const s8v*)(zl + row * 256 + ck * 8);
    }
    *(s8v*)(Ah + row * 256 + lswz(row, ck)) = vh;
    *(s8v*)(Al + row * 256 + lswz(row, ck)) = vl;
  }
  __syncthreads();
  const short* Bh = (const short*)wzh + (size_t)e * 65536;
  const short* Bl = (const short*)wzl + (size_t)e * 65536;
  f32x4 acc[2] = {};
#pragma unroll
  for (int kt = 0; kt < 8; ++kt) {
    const int ck = kt * 4 + l4;
    const s8v ah = *(const s8v*)(Ah + l15 * 256 + lswz(l15, ck));
    const s8v al = *(const s8v*)(Al + l15 * 256 + lswz(l15, ck));
#pragma unroll
    for (int nt = 0; nt < 2; ++nt) {
      const int ng = nb + wv * 32 + nt * 16;
      const size_t bo = ((size_t)(ng >> 4) * 8 + kt) * 512 + lane * 8;
      const s8v bh = *(const s8v*)(Bh + bo);
      const s8v bl = *(const s8v*)(Bl + bo);
      acc[nt] = MFMA(ah, bh, acc[nt], 0, 0, 0);
      acc[nt] = MFMA(al, bh, acc[nt], 0, 0, 0);
      acc[nt] = MFMA(ah, bl, acc[nt], 0, 0, 0);
    }
  }
#pragma unroll
  for (int nt = 0; nt < 2; ++nt) {
    const int col = nb + wv * 32 + nt * 16 + l15;
#pragma unroll
    for (int j = 0; j < 4; ++j) {
      const int row = l4 * 4 + j;
      if (row < nrows) {
        const int gr = e * 50 + r0 + row;
        const float v = acc[nt][j] + axw[((size_t)e * TB_ + t * 50 + r0 + row) * 256 + col];
        zP[(size_t)gr * 256 + col] = v;
        zPb[(size_t)gr * 256 + col] = __float2bfloat16(v);
      }
    }
  }
}

// K2: fh1 = relu(zPb @ W1fh + b1).  grid (22 rb16, 16 nt128)
__global__ __launch_bounds__(256, 2)
void k2_l1(const bf16* __restrict__ zPb, const bf16* __restrict__ w1f,
           const float* __restrict__ fb1, const float* __restrict__ hb1,
           bf16* __restrict__ fh1) {
  __shared__ short As[16 * 256];
  const int rb = blockIdx.x, nb = blockIdx.y * 128;
  const int r0 = rb * 16;
  const int tid = threadIdx.x, lane = tid & 63, wv = tid >> 6;
  const int l15 = lane & 15, l4 = lane >> 4;
#pragma unroll
  for (int i = 0; i < 2; ++i) {
    const int lin = tid + i * 256, row = lin >> 5, ck = lin & 31;
    s8v v = {};
    if (r0 + row < EB_)
      v = *(const s8v*)((const short*)zPb + (size_t)(r0 + row) * 256 + ck * 8);
    *(s8v*)(As + row * 256 + lswz(row, ck)) = v;
  }
  __syncthreads();
  f32x4 acc[2] = {};
#pragma unroll
  for (int kt = 0; kt < 8; ++kt) {
    const int ck = kt * 4 + l4;
    const s8v a = *(const s8v*)(As + l15 * 256 + lswz(l15, ck));
#pragma unroll
    for (int nt = 0; nt < 2; ++nt) {
      const int ng = nb + wv * 32 + nt * 16;
      const s8v b = *(const s8v*)((const short*)w1f + ((size_t)(ng >> 4) * 8 + kt) * 512 + lane * 8);
      acc[nt] = MFMA(a, b, acc[nt], 0, 0, 0);
    }
  }
#pragma unroll
  for (int nt = 0; nt < 2; ++nt) {
    const int col = nb + wv * 32 + nt * 16 + l15;
    const float bv = (col < 1024) ? fb1[col] : hb1[col - 1024];
#pragma unroll
    for (int j = 0; j < 4; ++j) {
      const int row = r0 + l4 * 4 + j;
      if (row < EB_)
        fh1[(size_t)row * 2048 + col] = __float2bfloat16(fmaxf(acc[nt][j] + bv, 0.f));
    }
  }
}

// K3+G: y<16 -> fh2 = tanh(fh1 @ W2 + b2); y>=16 -> g-function -> gv (global).
// grid (22 rb16, 20)
__global__ __launch_bounds__(256, 2)
void k3g(const bf16* __restrict__ fh1, const bf16* __restrict__ w2f,
         const float* __restrict__ fb2, const float* __restrict__ hb2,
         bf16* __restrict__ fh2, const float* __restrict__ zP,
         const _Float16* __restrict__ gpk, const float* __restrict__ gb2,
         float* __restrict__ gv) {
  __shared__ short As[16 * 1024];
  const int rb = blockIdx.x, nbl = blockIdx.y;
  const int tid = threadIdx.x, lane = tid & 63, wv = tid >> 6;
  const int l15 = lane & 15, l4 = lane >> 4;
  const int r0 = rb * 16;
  if (nbl >= 16) {
    float* ztile = (float*)As;
    const int c0 = (nbl - 16) * 64;
#pragma unroll
    for (int i = 0; i < 4; ++i) {
      const int lin = tid + i * 256, row = lin >> 6, col = lin & 63;
      ztile[row * 64 + col] =
          (r0 + row < EB_) ? zP[(size_t)(r0 + row) * 256 + c0 + col] : 1.0f;
    }
    __syncthreads();
    const int lloc = tid >> 2, hq = tid & 3;
    const _Float16* gl = gpk + (size_t)(c0 + lloc) * 3072 + hq * 256;
    f16x2 z2[16];
#pragma unroll
    for (int r = 0; r < 16; ++r) {
      const _Float16 zh_ = (_Float16)ztile[r * 64 + lloc];
      z2[r] = f16x2{zh_, zh_};
    }
    float ga[16] = {};
    for (int hp = 0; hp < 128; ++hp) {
      const f16x2 w1v = *(const f16x2*)(gl + 2 * hp);
      const f16x2 b1v = *(const f16x2*)(gl + 1024 + 2 * hp);
      const f16x2 w2v = *(const f16x2*)(gl + 2048 + 2 * hp);
#pragma unroll
      for (int r = 0; r < 16; ++r) {
        f16x2 tt = z2[r] * w1v + b1v;
#if __has_builtin(__builtin_elementwise_max)
        const f16x2 zz = {};
        tt = __builtin_elementwise_max(tt, zz);
#else
        tt[0] = tt[0] > (_Float16)0 ? tt[0] : (_Float16)0;
        tt[1] = tt[1] > (_Float16)0 ? tt[1] : (_Float16)0;
#endif
#if __has_builtin(__builtin_amdgcn_fdot2)
        ga[r] = __builtin_amdgcn_fdot2(tt, w2v, ga[r], false);
#else
        ga[r] += (float)tt[0] * (float)w2v[0] + (float)tt[1] * (float)w2v[1];
#endif
      }
    }
#pragma unroll
    for (int r = 0; r < 16; ++r) {
      float v = ga[r];
      v += __shfl_xor(v, 1, 64);
      v += __shfl_xor(v, 2, 64);
      if (hq == 0 && r0 + r < EB_)
        gv[(size_t)(r0 + r) * 256 + c0 + lloc] = v + gb2[c0 + lloc];
    }
    return;
  }
  const int nb = nbl * 128;
  const int half = (nbl >= 8) ? 1024 : 0;
#pragma unroll
  for (int i = 0; i < 8; ++i) {
    const int lin = tid + i * 256, row = lin >> 7, ck = lin & 127;
    s8v v = {};
    if (r0 + row < EB_)
      v = *(const s8v*)((const short*)fh1 + (size_t)(r0 + row) * 2048 + half + ck * 8);
    *(s8v*)(As + row * 1024 + lswz(row, ck)) = v;
  }
  __syncthreads();
  f32x4 acc[2] = {};
#pragma unroll 4
  for (int kt = 0; kt < 32; ++kt) {
    const int ck = kt * 4 + l4;
    const s8v a = *(const s8v*)(As + l15 * 1024 + lswz(l15, ck));
#pragma unroll
    for (int nt = 0; nt < 2; ++nt) {
      const int ng = nb + wv * 32 + nt * 16;
      const s8v b = *(const s8v*)((const short*)w2f + ((size_t)(ng >> 4) * 32 + kt) * 512 + lane * 8);
      acc[nt] = MFMA(a, b, acc[nt], 0, 0, 0);
    }
  }
#pragma unroll
  for (int nt = 0; nt < 2; ++nt) {
    const int col = nb + wv * 32 + nt * 16 + l15;
    const float bv = half ? hb2[col - 1024] : fb2[col];
#pragma unroll
    for (int j = 0; j < 4; ++j) {
      const int row = r0 + l4 * 4 + j;
      if (row < EB_)
        fh2[(size_t)row * 2048 + col] = __float2bfloat16(tanhf(acc[nt][j] + bv));
    }
  }
}

// K4: fv/hv GEMMs + epilogue (g read from gv).  grid (22 rb16, 4 cb64)
__global__ __launch_bounds__(256, 1)
void k4_fin(const bf16* __restrict__ fh2, const bf16* __restrict__ w3f,
            const float* __restrict__ fb3, const float* __restrict__ hb3,
            const float* __restrict__ gv, const float* __restrict__ zP,
            const float* __restrict__ dw, bf16* __restrict__ zhi,
            bf16* __restrict__ zlo, bf16* __restrict__ zs_bf,
            float* __restrict__ logqp, int t) {
  __shared__ short As[16 * 1024];
  __shared__ float ztile[16][64];
  __shared__ float ebuck[8];
  const int rb = blockIdx.x, cb = blockIdx.y;
  const int r0 = rb * 16, c0 = cb * 64;
  const int tid = threadIdx.x, lane = tid & 63, wv = tid >> 6;
  const int l15 = lane & 15, l4 = lane >> 4;
  if (tid < 8) ebuck[tid] = 0.f;
#pragma unroll
  for (int i = 0; i < 4; ++i) {
    const int lin = tid + i * 256, row = lin >> 6, col = lin & 63;
    ztile[row][col] = (r0 + row < EB_) ? zP[(size_t)(r0 + row) * 256 + c0 + col] : 1.0f;
  }
  f32x4 accF = {}, accH = {};
#pragma unroll
  for (int fb = 0; fb < 2; ++fb) {
    __syncthreads();
#pragma unroll
    for (int i = 0; i < 8; ++i) {
      const int lin = tid + i * 256, row = lin >> 7, ck = lin & 127;
      s8v v = {};
      if (r0 + row < EB_)
        v = *(const s8v*)((const short*)fh2 + (size_t)(r0 + row) * 2048 + fb * 1024 + ck * 8);
      *(s8v*)(As + row * 1024 + lswz(row, ck)) = v;
    }
    __syncthreads();
    const int ng = fb * 256 + c0 + wv * 16;
    f32x4 acc = {};
#pragma unroll 4
    for (int kt = 0; kt < 32; ++kt) {
      const int ck = kt * 4 + l4;
      const s8v a = *(const s8v*)(As + l15 * 1024 + lswz(l15, ck));
      const s8v b = *(const s8v*)((const short*)w3f + ((size_t)(ng >> 4) * 32 + kt) * 512 + lane * 8);
      acc = MFMA(a, b, acc, 0, 0, 0);
    }
    if (fb) accH = acc; else accF = acc;
  }
  __syncthreads();
  const int col_loc = wv * 16 + l15, col = c0 + col_loc;
  const float fb3v = fb3[col], hb3v = hb3[col];
#pragma unroll
  for (int j = 0; j < 4; ++j) {
    const int rl = l4 * 4 + j, row = r0 + rl;
    if (row < EB_) {
      const float fv = accF[j] + fb3v;
      const float hv = accH[j] + hb3v;
      const float gvv = gv[(size_t)row * 256 + col];
      const float u = (fv - hv) / gvv;
      atomicAdd(&ebuck[row / 50], 0.001f * u * u);
      const float znew = ztile[rl][col_loc] + 0.1f * fv +
                         gvv * (SQRTH * dw[(size_t)t * (EB_ * 256) + (size_t)row * 256 + col]);
      const bf16 h = __float2bfloat16(znew);
      const size_t zi = (size_t)row * 256 + col;
      zhi[zi] = h;
      zlo[zi] = __float2bfloat16(znew - __bfloat162float(h));
      const int e = row / 50, b = row - e * 50;
      zs_bf[((size_t)e * TB_ + t * 50 + b) * 256 + col] = h;
    }
  }
  __syncthreads();
  if (tid < 7) {
    const float v = ebuck[tid];
    if (v != 0.f) atomicAdd(&logqp[tid], v);
  }
}

__global__ void init_kernel(float* logqp) {
  if (threadIdx.x < E_) logqp[threadIdx.x] = 0.f;
}

extern "C" void kernel_launch(void* const* d_in, const int* in_sizes, int n_in,
                              void* d_out, int out_size, void* d_ws, size_t ws_size,
                              hipStream_t stream) {
  (void)in_sizes; (void)n_in; (void)out_size;
  const float* enc_w1 = (const float*)d_in[0];
  const float* enc_b1 = (const float*)d_in[1];
  const float* enc_w2 = (const float*)d_in[2];
  const float* enc_b2 = (const float*)d_in[3];
  const float* enc_w3 = (const float*)d_in[4];
  const float* enc_b3 = (const float*)d_in[5];
  const float* qz0_w  = (const float*)d_in[6];
  const float* qz0_b  = (const float*)d_in[7];
  const float* act_w  = (const float*)d_in[8];
  const float* act_b  = (const float*)d_in[9];
  const float* proj_w1 = (const float*)d_in[10];
  const float* proj_b1 = (const float*)d_in[11];
  const float* proj_w2 = (const float*)d_in[12];
  const float* proj_b2 = (const float*)d_in[13];
  const float* proj_w3 = (const float*)d_in[14];
  const float* proj_b3 = (const float*)d_in[15];
  const float* f_w1 = (const float*)d_in[16];
  const float* f_b1 = (const float*)d_in[17];
  const float* f_w2 = (const float*)d_in[18];
  const float* f_b2 = (const float*)d_in[19];
  const float* f_w3 = (const float*)d_in[20];
  const float* f_b3 = (const float*)d_in[21];
  const float* h_w1 = (const float*)d_in[22];
  const float* h_b1 = (const float*)d_in[23];
  const float* h_w2 = (const float*)d_in[24];
  const float* h_b2 = (const float*)d_in[25];
  const float* h_w3 = (const float*)d_in[26];
  const float* h_b3 = (const float*)d_in[27];
  const float* g_w1 = (const float*)d_in[28];
  const float* g_b1 = (const float*)d_in[29];
  const float* g_w2 = (const float*)d_in[30];
  const float* g_b2 = (const float*)d_in[31];
  const float* pz0_mean   = (const float*)d_in[32];
  const float* pz0_logstd = (const float*)d_in[33];
  const float* xs      = (const float*)d_in[34];
  const float* actions = (const float*)d_in[35];
  const float* eps_z0  = (const float*)d_in[36];
  const float* dw      = (const float*)d_in[37];

  float* out = (float*)d_out;
  float* logqp = out;
  float* pred = out + E_;

  char* base = (char*)d_ws;
  size_t off = 0;
  auto alloc = [&](size_t bytes) {
    void* p = base + off;
    off = (off + bytes + 255) & ~(size_t)255;
    return p;
  };
  bf16* zhi    = (bf16*)alloc((size_t)EB_ * 256 * 2);
  bf16* zlo    = (bf16*)alloc((size_t)EB_ * 256 * 2);
  float* zP    = (float*)alloc((size_t)EB_ * 256 * 4);
  bf16* zPb    = (bf16*)alloc((size_t)EB_ * 256 * 2);
  bf16* fh1    = (bf16*)alloc((size_t)EB_ * 2048 * 2);
  bf16* fh2    = (bf16*)alloc((size_t)EB_ * 2048 * 2);
  float* gvb   = (float*)alloc((size_t)EB_ * 256 * 4);
  bf16* zs_bf  = (bf16*)alloc((size_t)E_ * T_ * B_ * 256 * 2);
  float* axw   = (float*)alloc((size_t)E_ * TB_ * 256 * 4);
  bf16* ax_bf  = (bf16*)alloc((size_t)E_ * TB_ * 192 * 2);
  bf16* waxT   = (bf16*)alloc((size_t)E_ * 256 * 192 * 2);
  bf16* wzh    = (bf16*)alloc((size_t)E_ * 65536 * 2);
  bf16* wzl    = (bf16*)alloc((size_t)E_ * 65536 * 2);
  bf16* w1f    = (bf16*)alloc((size_t)2048 * 256 * 2);
  bf16* w2f    = (bf16*)alloc((size_t)2048 * 1024 * 2);
  bf16* w3f    = (bf16*)alloc((size_t)512 * 1024 * 2);
  _Float16* gpk = (_Float16*)alloc((size_t)256 * 3 * 1024 * 2);
  bf16* xs_bf  = (bf16*)alloc((size_t)E_ * TB_ * D_ * 2);
  bf16* ew1T = (bf16*)alloc((size_t)E_ * D_ * H_ * 2);
  bf16* ew2T = (bf16*)alloc((size_t)E_ * H_ * H_ * 2);
  bf16* ew3T = (bf16*)alloc((size_t)E_ * H_ * C_ * 2);
  bf16* pw1T = (bf16*)alloc((size_t)E_ * L_ * H_ * 2);
  bf16* pw2T = (bf16*)alloc((size_t)E_ * H_ * H_ * 2);
  bf16* pw3T = (bf16*)alloc((size_t)E_ * H_ * D_ * 2);
  const size_t per_row = (size_t)E_ * (H_ * 2 * 2 + C_ * 4);
  size_t remain = (ws_size > off + 4096) ? (ws_size - off - 4096) : 0;
  int CH = (int)(remain / per_row);
  if (CH > 2500) CH = 2500;
  if (CH < 64) CH = 64;
  bf16* bufA = (bf16*)alloc((size_t)E_ * CH * H_ * 2);
  bf16* bufB = (bf16*)alloc((size_t)E_ * CH * H_ * 2);
  float* bufC = (float*)alloc((size_t)E_ * CH * C_ * 4);

  init_kernel<<<dim3(1), dim3(64), 0, stream>>>(logqp);

  const dim3 cb256(256);
  cvt_kernel<<<dim3((E_ * TB_ * D_ / 4 + 255) / 256), cb256, 0, stream>>>(xs, xs_bf, E_ * TB_ * D_ / 4);
  cvtT_kernel<<<dim3(H_ / 32, D_ / 32, E_), cb256, 0, stream>>>(enc_w1, ew1T, D_, H_, (long)D_ * H_, (long)D_ * H_);
  cvtT_kernel<<<dim3(H_ / 32, H_ / 32, E_), cb256, 0, stream>>>(enc_w2, ew2T, H_, H_, (long)H_ * H_, (long)H_ * H_);
  cvtT_kernel<<<dim3(C_ / 32, H_ / 32, E_), cb256, 0, stream>>>(enc_w3, ew3T, H_, C_, (long)H_ * C_, (long)H_ * C_);
  cvtT_kernel<<<dim3(H_ / 32, L_ / 32, E_), cb256, 0, stream>>>(proj_w1, pw1T, L_, H_, (long)L_ * H_, (long)L_ * H_);
  cvtT_kernel<<<dim3(H_ / 32, H_ / 32, E_), cb256, 0, stream>>>(proj_w2, pw2T, H_, H_, (long)H_ * H_, (long)H_ * H_);
  cvtT_kernel<<<dim3(D_ / 32, H_ / 32, E_), cb256, 0, stream>>>(proj_w3, pw3T, H_, D_, (long)H_ * D_, (long)H_ * D_);
  ax_build<<<dim3((E_ * TB_ * 192 + 255) / 256), cb256, 0, stream>>>(actions, xs, ax_bf);
  waxT_build<<<dim3((E_ * 256 * 192 + 255) / 256), cb256, 0, stream>>>(act_w, waxT);
  packWz<<<dim3((E_ * 65536 + 255) / 256), cb256, 0, stream>>>(act_w, wzh, wzl);
  packW<<<dim3((256 * 1024 + 255) / 256), cb256, 0, stream>>>(f_w1, w1f, 256, 1024);
  packW<<<dim3((256 * 1024 + 255) / 256), cb256, 0, stream>>>(h_w1, w1f + (size_t)1024 * 256, 256, 1024);
  packW<<<dim3((1024 * 1024 + 255) / 256), cb256, 0, stream>>>(f_w2, w2f, 1024, 1024);
  packW<<<dim3((1024 * 1024 + 255) / 256), cb256, 0, stream>>>(h_w2, w2f + (size_t)1024 * 1024, 1024, 1024);
  packW<<<dim3((1024 * 256 + 255) / 256), cb256, 0, stream>>>(f_w3, w3f, 1024, 256);
  packW<<<dim3((1024 * 256 + 255) / 256), cb256, 0, stream>>>(h_w3, w3f + (size_t)256 * 1024, 1024, 256);
  gpack_build<<<dim3((256 * 3 * 1024 + 255) / 256), cb256, 0, stream>>>(g_w1, g_b1, g_w2, gpk);

  BG g;
  // axw = ax @ WaxT + act_b  (all t, f32)
  for (int e = 0; e < E_; ++e) {
    g.A[e] = ax_bf + (size_t)e * TB_ * 192;
    g.W[e] = waxT + (size_t)e * 256 * 192;
    g.bias[e] = act_b + (size_t)e * 256;
    g.Cf[e] = axw + (size_t)e * TB_ * 256;
  }
  bgemm<128, 0, 0><<<dim3((TB_ + 127) / 128, 2, E_), 256, 0, stream>>>(g, TB_, 192, 192, 192, 256);

  // ---- Phase A: encoder + q/KL (+z0 split into zhi/zlo) ----
  for (int c = 0; c < TB_; c += CH) {
    const int rows = (TB_ - c < CH) ? (TB_ - c) : CH;
    const int mt = (rows + 127) / 128;
    for (int e = 0; e < E_; ++e) {
      g.A[e] = xs_bf + ((size_t)e * TB_ + c) * D_;
      g.W[e] = ew1T + (size_t)e * D_ * H_;
      g.bias[e] = enc_b1 + (size_t)e * H_;
      g.Cb[e] = bufA + (size_t)e * CH * H_;
    }
    bgemm<128, 1, 1><<<dim3(mt, H_ / 128, E_), 256, 0, stream>>>(g, rows, D_, D_, D_, H_);
    for (int e = 0; e < E_; ++e) {
      g.A[e] = bufA + (size_t)e * CH * H_;
      g.W[e] = ew2T + (size_t)e * H_ * H_;
      g.bias[e] = enc_b2 + (size_t)e * H_;
      g.Cb[e] = bufB + (size_t)e * CH * H_;
    }
    bgemm<128, 1, 1><<<dim3(mt, H_ / 128, E_), 256, 0, stream>>>(g, rows, H_, H_, H_, H_);
    for (int e = 0; e < E_; ++e) {
      g.A[e] = bufB + (size_t)e * CH * H_;
      g.W[e] = ew3T + (size_t)e * H_ * C_;
      g.bias[e] = enc_b3 + (size_t)e * C_;
      g.Cf[e] = bufC + (size_t)e * CH * C_;
    }
    bgemm<128, 0, 0><<<dim3(mt, C_ / 128, E_), 256, 0, stream>>>(g, rows, H_, H_, H_, C_);
    qkl_kernel<<<dim3((rows + 15) / 16, E_), 256, 0, stream>>>(
        bufC, rows, c, CH * C_, qz0_w, qz0_b, pz0_mean, pz0_logstd, eps_z0,
        zhi, zlo, logqp);
  }

  // ---- Scan: 4 kernels per step (g overlapped with L2 in k3g) ----
  for (int t = 0; t < T_; ++t) {
    k1_act<<<dim3(4, 2, E_), 256, 0, stream>>>(zhi, zlo, wzh, wzl, axw, zP, zPb, t);
    k2_l1<<<dim3(22, 16), 256, 0, stream>>>(zPb, w1f, f_b1, h_b1, fh1);
    k3g<<<dim3(22, 20), 256, 0, stream>>>(fh1, w2f, f_b2, h_b2, fh2,
                                          zP, gpk, g_b2, gvb);
    k4_fin<<<dim3(22, 4), 256, 0, stream>>>(fh2, w3f, f_b3, h_b3, gvb,
                                            zP, dw, zhi, zlo, zs_bf, logqp, t);
  }

  // ---- Projector ----
  for (int c = 0; c < TB_; c += CH) {
    const int rows = (TB_ - c < CH) ? (TB_ - c) : CH;
    const int mt = (rows + 127) / 128;
    for (int e = 0; e < E_; ++e) {
      g.A[e] = zs_bf + ((size_t)e * T_ * B_ + c) * L_;
      g.W[e] = pw1T + (size_t)e * L_ * H_;
      g.bias[e] = proj_b1 + (size_t)e * H_;
      g.Cb[e] = bufA + (size_t)e * CH * H_;
    }
    bgemm<128, 2, 1><<<dim3(mt, H_ / 128, E_), 256, 0, stream>>>(g, rows, L_, L_, L_, H_);
    for (int e = 0; e < E_; ++e) {
      g.A[e] = bufA + (size_t)e * CH * H_;
      g.W[e] = pw2T + (size_t)e * H_ * H_;
      g.bias[e] = proj_b2 + (size_t)e * H_;
      g.Cb[e] = bufB + (size_t)e * CH * H_;
    }
    bgemm<128, 2, 1><<<dim3(mt, H_ / 128, E_), 256, 0, stream>>>(g, rows, H_, H_, H_, H_);
    for (int e = 0; e < E_; ++e) {
      g.A[e] = bufB + (size_t)e * CH * H_;
      g.W[e] = pw3T + (size_t)e * H_ * D_;
      g.bias[e] = proj_b3 + (size_t)e * D_;
      g.Cf[e] = pred + ((size_t)e * TB_ + c) * D_;
    }
    bgemm<128, 0, 0><<<dim3(mt, D_ / 128, E_), 256, 0, stream>>>(g, rows, H_, H_, H_, D_);
  }
}